// Round 16
// baseline (404.914 us; speedup 1.0000x reference)
//
#include <hip/hip_runtime.h>

typedef _Float16 f16;
typedef _Float16 f16x8 __attribute__((ext_vector_type(8)));
typedef _Float16 f16x4 __attribute__((ext_vector_type(4)));
typedef float f32x4 __attribute__((ext_vector_type(4)));

#define B_    2048
#define I_    1024
#define H_    2048
#define C_    1000
#define S_    8
#define N1    32768   /* S * 2H */
#define TOPK_ 256

// ---------------- global -> LDS async stage (16B per lane) ----------------
__device__ __forceinline__ void gload16(const void* g, void* l) {
  __builtin_amdgcn_global_load_lds((const __attribute__((address_space(1))) void*)g,
                                   (__attribute__((address_space(3))) void*)l,
                                   16, 0, 0);
}

// ---------------- merged prep: x/gW/cW converts + phase tables ----------
// (W is NOT converted -- gemm1 stages it in f32 via global_load_lds)
#define NX8  (B_ * I_ / 8)
#define NG8  (H_ * H_ / 8)
#define NC8  (1024 * H_ / 8)
#define NPH  (S_ * H_)
#define NTOT (NX8 + NG8 + NC8 + NPH)

__global__ void prep_kernel(const float* __restrict__ x,
                            const float* __restrict__ gW, const float* __restrict__ cW,
                            const float* __restrict__ ph,
                            f16* __restrict__ xf,
                            f16* __restrict__ gWf, f16* __restrict__ cWf,
                            float* __restrict__ cphi, float* __restrict__ sphi)
{
  int i = blockIdx.x * blockDim.x + threadIdx.x;
  if (i >= NTOT) return;
  if (i < NX8 + NG8 + NC8) {
    const float* src;
    f16* dst;
    int j = i;
    bool pad = false;
    if (j < NX8)                { src = x;  dst = xf; }
    else if ((j -= NX8) < NG8)  { src = gW; dst = gWf; }
    else {
      j -= NG8; src = cW; dst = cWf;
      pad = (j >= C_ * H_ / 8);
    }
    f16x8 o;
    if (!pad) {
      const float4 a = reinterpret_cast<const float4*>(src)[2 * j];
      const float4 b = reinterpret_cast<const float4*>(src)[2 * j + 1];
      o = (f16x8){ (f16)a.x, (f16)a.y, (f16)a.z, (f16)a.w,
                   (f16)b.x, (f16)b.y, (f16)b.z, (f16)b.w };
    } else {
      o = (f16x8){ (f16)0.f, (f16)0.f, (f16)0.f, (f16)0.f,
                   (f16)0.f, (f16)0.f, (f16)0.f, (f16)0.f };
    }
    reinterpret_cast<f16x8*>(dst)[j] = o;
  } else {
    int j = i - (NX8 + NG8 + NC8);
    float p = ph[j];
    cphi[j] = cosf(p);
    sphi[j] = sinf(p);
  }
}

// ================= GEMM1: 256x256, BK=32 ring, 8 waves, W staged in f32 ======
// A (x, f16): ring-4 x 16KB @0, distance-3, 2 gload16/subtile (proven path).
// B (W, f32): ring-2 x 32KB @65536, distance-1, 4 gload16/subtile; rows 128B,
//   LDS[r][chunk16B] = src[r][chunk ^ (r&7)]; read chunk (2fq+h)^(fr&7) ->
//   uniform bank spread. ds_read two f32x4/frag, cvt f32->f16 in-register
//   (identical rounding to the old prep convert -> bitwise-same MFMA inputs).
// Issue order: B(t+1) then A(t+3); end-of-subtile vmcnt(2) confirms
// A(t+1),A(t+2),B(t+1), leaves A(t+3) in flight. One barrier per subtile.
__global__ __launch_bounds__(512, 1)
void gemm1_wf32(const f16* __restrict__ A, const float* __restrict__ BW,
                const float* __restrict__ bias, f16* __restrict__ act)
{
  __shared__ char SL[131072];
  const int tid = threadIdx.x, lane = tid & 63, wid = tid >> 6;
  const int wr = wid >> 2, wc = wid & 3;       // 2M x 4N wave grid
  const int fr = lane & 15, fq = lane >> 4;
  const int bid = blockIdx.x;
  const int swz = (bid & 7) * 128 + (bid >> 3);   // XCD swizzle, 1024 blocks
  const int mt = swz & 7, nt = swz >> 3;
  const long brow = (long)mt * 256, bcol = (long)nt * 256;

  // A staging: call a covers rows a*128 + tid/4, chunk tid&3, key (r>>1)&3
  const int schunkA = ((tid & 3) ^ ((tid >> 3) & 3)) * 8;
  const f16* srcA0 = A + (brow + (tid >> 2)) * (long)I_ + schunkA;
  const f16* srcA1 = A + (brow + 128 + (tid >> 2)) * (long)I_ + schunkA;

  // B staging (f32): call a covers rows a*64 + tid/8, chunk tid&7, key r&7
  const int schunkB = ((tid & 7) ^ ((tid >> 3) & 7)) * 4;   // f32 elems
  const float* srcBp[4];
#pragma unroll
  for (int a = 0; a < 4; ++a)
    srcBp[a] = BW + (bcol + a * 64 + (tid >> 3)) * (size_t)I_ + schunkB;

  // read offsets
  const int coA  = (fq ^ ((fr >> 1) & 3)) * 16;
  const int rdA0 = (wr * 128 + fr) * 64 + coA;
  const int rB0  = (wc * 64 + fr) * 128;                 // + n*2048
  const int cB0  = ((fq * 2) ^ (fr & 7)) * 16;           // h0 chunk
  const int cB1  = cB0 ^ 16;                             // h1 chunk

  f32x4 acc[8][4] = {};

#define STGA(a, tt)                                                     \
  gload16(((a) ? srcA1 : srcA0) + (size_t)(tt) * 32,                    \
          SL + ((tt) & 3) * 16384 + ((a) * 512 + tid) * 16)
#define STGB(a, tt)                                                     \
  gload16(srcBp[a] + (size_t)(tt) * 32,                                 \
          SL + 65536 + ((tt) & 1) * 32768 + (a) * 8192 + tid * 16)

  // prologue: A0, B0 (oldest), then A1, A2
  STGA(0,0); STGA(1,0);
  STGB(0,0); STGB(1,0); STGB(2,0); STGB(3,0);
  STGA(0,1); STGA(1,1);
  STGA(0,2); STGA(1,2);
  asm volatile("s_waitcnt vmcnt(4)" ::: "memory");   // A0+B0 done; A1,A2 in flight
  __builtin_amdgcn_s_barrier();

#pragma unroll 1
  for (int t = 0; t < 32; ++t) {
    const char* ra  = SL + (t & 3) * 16384;
    const char* rbB = SL + 65536 + (t & 1) * 32768;
    if (t < 31) { STGB(0, t + 1); STGB(1, t + 1); STGB(2, t + 1); STGB(3, t + 1); }
    if (t < 29) { STGA(0, t + 3); STGA(1, t + 3); }

    f16x8 bf[4], af[8];
#pragma unroll
    for (int n = 0; n < 4; ++n) {
      const f32x4 u0 = *(const f32x4*)(rbB + n * 2048 + rB0 + cB0);
      const f32x4 u1 = *(const f32x4*)(rbB + n * 2048 + rB0 + cB1);
      bf[n] = (f16x8){ (f16)u0[0], (f16)u0[1], (f16)u0[2], (f16)u0[3],
                       (f16)u1[0], (f16)u1[1], (f16)u1[2], (f16)u1[3] };
    }
#pragma unroll
    for (int i = 0; i < 8; ++i) af[i] = *(const f16x8*)(ra + rdA0 + i * 1024);

    __builtin_amdgcn_s_setprio(1);
#pragma unroll
    for (int i = 0; i < 8; ++i)
#pragma unroll
      for (int n = 0; n < 4; ++n)
        acc[i][n] = __builtin_amdgcn_mfma_f32_16x16x32_f16(af[i], bf[n], acc[i][n], 0, 0, 0);
    __builtin_amdgcn_s_setprio(0);

    if (t < 29) asm volatile("s_waitcnt vmcnt(2)" ::: "memory");
    else        asm volatile("s_waitcnt vmcnt(0)" ::: "memory");
    __builtin_amdgcn_s_barrier();
  }
#undef STGA
#undef STGB

  // epilogue: act = exp(-(acc+bias)^2)
  float bv[4];
#pragma unroll
  for (int n = 0; n < 4; ++n) bv[n] = bias[bcol + wc * 64 + n * 16 + fr];
#pragma unroll
  for (int m = 0; m < 8; ++m) {
    const long r0 = brow + wr * 128 + m * 16 + fq * 4;
#pragma unroll
    for (int n = 0; n < 4; ++n) {
      const long c = bcol + wc * 64 + n * 16 + fr;
#pragma unroll
      for (int j = 0; j < 4; ++j) {
        const float tt = acc[m][n][j] + bv[n];
        act[(r0 + j) * (long)N1 + c] = (f16)__expf(-tt * tt);
      }
    }
  }
}

// ================= generic ring-4 pipelined GEMM (gates / clf) =================
template<int BM, int BN, int WM, int WN, int THREADS, int MINW, int EPI>
__global__ __launch_bounds__(THREADS, MINW)
void gemm_ring(const f16* __restrict__ A, const f16* __restrict__ Bmat,
               const int K, const int MT, const int ldc, const int nreal,
               const float* __restrict__ bias,
               const float* __restrict__ magin,
               float* __restrict__ mago32, f16* __restrict__ mago16,
               float* __restrict__ msqout, float* __restrict__ logits)
{
  constexpr int MREP  = BM / (WM * 16);
  constexpr int NREP  = BN / (WN * 16);
  constexpr int CA    = (BM * 64) / (THREADS * 16);
  constexpr int CB    = (BN * 64) / (THREADS * 16);
  constexpr int CALLS = CA + CB;
  constexpr int SLOT  = (BM + BN) * 32;
  __shared__ f16 SL[4 * SLOT];

  const int tid  = threadIdx.x;
  const int lane = tid & 63, wid = tid >> 6;
  const int wr = wid / WN, wc = wid % WN;
  const int fr = lane & 15, fq = lane >> 4;

  const int nwg = gridDim.x;
  const int chunk = nwg >> 3;
  const int swz = (blockIdx.x & 7) * chunk + (blockIdx.x >> 3);
  const int mt = swz % MT, nt = swz / MT;
  const long brow = (long)mt * BM, bcol = (long)nt * BN;

  const f16* srcA[CA];
  const f16* srcB[CB];
#pragma unroll
  for (int a = 0; a < CA; ++a) {
    const int r = (a * THREADS + tid) >> 2;
    const int cs = (tid & 3) ^ ((r >> 1) & 3);
    srcA[a] = A + (size_t)(brow + r) * K + cs * 8;
  }
#pragma unroll
  for (int a = 0; a < CB; ++a) {
    const int r = (a * THREADS + tid) >> 2;
    const int cs = (tid & 3) ^ ((r >> 1) & 3);
    srcB[a] = Bmat + (size_t)(bcol + r) * K + cs * 8;
  }

  int ard[MREP], brd[NREP];
#pragma unroll
  for (int m = 0; m < MREP; ++m) {
    const int r = wr * MREP * 16 + m * 16 + fr;
    ard[m] = r * 32 + ((fq ^ ((r >> 1) & 3)) * 8);
  }
#pragma unroll
  for (int n = 0; n < NREP; ++n) {
    const int r = wc * NREP * 16 + n * 16 + fr;
    brd[n] = r * 32 + ((fq ^ ((r >> 1) & 3)) * 8);
  }

  f32x4 acc[MREP][NREP] = {};
  const int ntile = K >> 5;

#define STAGE_TILE(tt)                                                         \
  do {                                                                         \
    f16* D = &SL[((tt) & 3) * SLOT];                                           \
    const long kt = (long)(tt) * 32;                                           \
    _Pragma("unroll")                                                          \
    for (int a = 0; a < CA; ++a)                                               \
      gload16(srcA[a] + kt, D + a * THREADS * 8 + wid * 512);                  \
    _Pragma("unroll")                                                          \
    for (int a = 0; a < CB; ++a)                                               \
      gload16(srcB[a] + kt, D + BM * 32 + a * THREADS * 8 + wid * 512);        \
  } while (0)

  STAGE_TILE(0); STAGE_TILE(1); STAGE_TILE(2);

  for (int t = 0; t < ntile; ++t) {
    if (t + 3 < ntile) STAGE_TILE(t + 3);
    if (t < ntile - 3)       asm volatile("s_waitcnt vmcnt(%0)" :: "i"(3 * CALLS) : "memory");
    else if (t == ntile - 3) asm volatile("s_waitcnt vmcnt(%0)" :: "i"(2 * CALLS) : "memory");
    else if (t == ntile - 2) asm volatile("s_waitcnt vmcnt(%0)" :: "i"(1 * CALLS) : "memory");
    else                     asm volatile("s_waitcnt vmcnt(0)" ::: "memory");
    __builtin_amdgcn_s_barrier();
    asm volatile("" ::: "memory");

    const f16* SA = &SL[(t & 3) * SLOT];
    const f16* SB = SA + BM * 32;
    f16x8 af[MREP], bf[NREP];
#pragma unroll
    for (int m = 0; m < MREP; ++m) af[m] = *(const f16x8*)(SA + ard[m]);
#pragma unroll
    for (int n = 0; n < NREP; ++n) bf[n] = *(const f16x8*)(SB + brd[n]);

    __builtin_amdgcn_s_setprio(1);
#pragma unroll
    for (int m = 0; m < MREP; ++m)
#pragma unroll
      for (int n = 0; n < NREP; ++n)
        acc[m][n] = __builtin_amdgcn_mfma_f32_16x16x32_f16(af[m], bf[n], acc[m][n], 0, 0, 0);
    __builtin_amdgcn_s_setprio(0);
    asm volatile("" ::: "memory");
    __builtin_amdgcn_s_barrier();
  }
#undef STAGE_TILE

#pragma unroll
  for (int m = 0; m < MREP; ++m) {
    const long r0 = brow + wr * MREP * 16 + m * 16 + fq * 4;
#pragma unroll
    for (int n = 0; n < NREP; ++n) {
      const long c = bcol + wc * NREP * 16 + n * 16 + fr;
      float bv;
      if (EPI == 2) bv = (c < nreal) ? bias[c] : 0.f;
      else          bv = bias[c];
#pragma unroll
      for (int j = 0; j < 4; ++j) {
        const long r = r0 + j;
        const float t = acc[m][n][j] + bv;
        if (EPI == 1) {
          const float g = 1.f / (1.f + __expf(-t));
          const long idx = r * (long)ldc + c;
          const float v = magin[idx] * g;
          if (msqout) msqout[idx] = v * v;
          else { mago32[idx] = v; mago16[idx] = (f16)v; }
        } else {
          if (c < nreal) logits[r * (long)nreal + c] = t;
        }
      }
    }
  }
}

// ---------------- per-row norm + supposition -> mag0 (LDS version, proven) ----
__global__ __launch_bounds__(512)
void normsup_kernel(const f16* __restrict__ act,
                    const float* __restrict__ cphi, const float* __restrict__ sphi,
                    float* __restrict__ mag32, f16* __restrict__ mag16)
{
  __shared__ float buf[4096];
  __shared__ float red[8];
  const int b = blockIdx.x, tid = threadIdx.x;
  const int lane = tid & 63, wv = tid >> 6;
  float sr[4] = {0, 0, 0, 0}, si[4] = {0, 0, 0, 0};
  const f16* base = act + (size_t)b * N1;

  for (int s = 0; s < S_; ++s) {
    f16x8 v = *(const f16x8*)(base + s * 4096 + tid * 8);
    float ls = 0.f;
#pragma unroll
    for (int e = 0; e < 8; ++e) {
      float f = (float)v[e];
      buf[tid * 8 + e] = f;
      ls += f * f;
    }
#pragma unroll
    for (int o = 32; o > 0; o >>= 1) ls += __shfl_down(ls, o);
    if (lane == 0) red[wv] = ls;
    __syncthreads();
    const float tot = red[0] + red[1] + red[2] + red[3] + red[4] + red[5] + red[6] + red[7];
    const float factor = 1.f / sqrtf(tot + 1e-8f);

    const float4 c4 = *(const float4*)(cphi + s * H_ + tid * 4);
    const float4 s4 = *(const float4*)(sphi + s * H_ + tid * 4);
    const float4 a4 = *(const float4*)(&buf[tid * 4]);
    const float4 b4 = *(const float4*)(&buf[2048 + tid * 4]);
    sr[0] += factor * (a4.x * c4.x - b4.x * s4.x); si[0] += factor * (a4.x * s4.x + b4.x * c4.x);
    sr[1] += factor * (a4.y * c4.y - b4.y * s4.y); si[1] += factor * (a4.y * s4.y + b4.y * c4.y);
    sr[2] += factor * (a4.z * c4.z - b4.z * s4.z); si[2] += factor * (a4.z * s4.z + b4.z * c4.z);
    sr[3] += factor * (a4.w * c4.w - b4.w * s4.w); si[3] += factor * (a4.w * s4.w + b4.w * c4.w);
    __syncthreads();
  }

  const size_t o = (size_t)b * H_ + tid * 4;
  const float m0 = sqrtf(sr[0] * sr[0] + si[0] * si[0]);
  const float m1 = sqrtf(sr[1] * sr[1] + si[1] * si[1]);
  const float m2 = sqrtf(sr[2] * sr[2] + si[2] * si[2]);
  const float m3 = sqrtf(sr[3] * sr[3] + si[3] * si[3]);
  *(float4*)(mag32 + o) = make_float4(m0, m1, m2, m3);
  f16x4 mh = { (f16)m0, (f16)m1, (f16)m2, (f16)m3 };
  *(f16x4*)(mag16 + o) = mh;
}

// ---------------- top-k (256 of 2048) + prob normalize ----------------
__global__ __launch_bounds__(256)
void topk_kernel(const float* __restrict__ msq, f16* __restrict__ probs)
{
  __shared__ unsigned vals[2048];
  __shared__ int hist[256];
  __shared__ int scn[256];
  __shared__ int sdig, sknew;
  __shared__ float wsum[4];
  const int b = blockIdx.x, tid = threadIdx.x;
  const unsigned* row = (const unsigned*)(msq + (size_t)b * H_);

  uint4 v0 = *(const uint4*)(row + tid * 8);
  uint4 v1 = *(const uint4*)(row + tid * 8 + 4);
  vals[tid * 8 + 0] = v0.x; vals[tid * 8 + 1] = v0.y;
  vals[tid * 8 + 2] = v0.z; vals[tid * 8 + 3] = v0.w;
  vals[tid * 8 + 4] = v1.x; vals[tid * 8 + 5] = v1.y;
  vals[tid * 8 + 6] = v1.z; vals[tid * 8 + 7] = v1.w;
  __syncthreads();

  int k = TOPK_;
  unsigned prefix = 0, pmask = 0;
  for (int pass = 0; pass < 4; ++pass) {
    const int sh = 24 - pass * 8;
    hist[tid] = 0;
    __syncthreads();
#pragma unroll
    for (int e = 0; e < 8; ++e) {
      unsigned v = vals[tid * 8 + e];
      if ((v & pmask) == prefix) atomicAdd(&hist[(v >> sh) & 255u], 1);
    }
    __syncthreads();
    const int own = hist[tid];
    int sc = own;
    scn[tid] = sc;
    __syncthreads();
    for (int o2 = 1; o2 < 256; o2 <<= 1) {
      int add = (tid + o2 < 256) ? scn[tid + o2] : 0;
      __syncthreads();
      sc += add; scn[tid] = sc;
      __syncthreads();
    }
    if (sc >= k && (sc - own) < k) { sdig = tid; sknew = k - (sc - own); }
    __syncthreads();
    prefix |= ((unsigned)sdig) << sh;
    pmask  |= 0xFFu << sh;
    k = sknew;
    __syncthreads();
  }

  const unsigned T = prefix;
  const int krem = k;
  unsigned vl[8];
  int eqc = 0;
#pragma unroll
  for (int e = 0; e < 8; ++e) { vl[e] = vals[tid * 8 + e]; if (vl[e] == T) eqc++; }
  int sc2 = eqc;
  scn[tid] = sc2;
  __syncthreads();
  for (int o2 = 1; o2 < 256; o2 <<= 1) {
    int add = (tid >= o2) ? scn[tid - o2] : 0;
    __syncthreads();
    sc2 += add; scn[tid] = sc2;
    __syncthreads();
  }
  int rank = sc2 - eqc;
  float ls = 0.f;
  bool sel[8];
#pragma unroll
  for (int e = 0; e < 8; ++e) {
    const unsigned v = vl[e];
    bool s_ = false;
    if (v > T) s_ = true;
    else if (v == T) { s_ = (rank < krem); ++rank; }
    sel[e] = s_;
    if (s_) ls += __uint_as_float(v);
  }
#pragma unroll
  for (int o2 = 32; o2 > 0; o2 >>= 1) ls += __shfl_down(ls, o2);
  if ((tid & 63) == 0) wsum[tid >> 6] = ls;
  __syncthreads();
  const float tot = wsum[0] + wsum[1] + wsum[2] + wsum[3];
  const float inv = 1.f / (tot + 1e-8f);
  f16x8 ov;
#pragma unroll
  for (int e = 0; e < 8; ++e)
    ov[e] = sel[e] ? (f16)(__uint_as_float(vl[e]) * inv) : (f16)0.f;
  *(f16x8*)(probs + (size_t)b * H_ + tid * 8) = ov;
}

// ---------------- launch ----------------
extern "C" void kernel_launch(void* const* d_in, const int* in_sizes, int n_in,
                              void* d_out, int out_size, void* d_ws, size_t ws_size,
                              hipStream_t stream)
{
  const float* x  = (const float*)d_in[0];
  const float* W  = (const float*)d_in[1];
  const float* bb = (const float*)d_in[2];
  const float* ph = (const float*)d_in[3];
  const float* gW = (const float*)d_in[4];
  const float* gb = (const float*)d_in[5];
  const float* cW = (const float*)d_in[6];
  const float* cb = (const float*)d_in[7];
  float* out = (float*)d_out;

  char* base = (char*)d_ws;
  size_t off = 0;
  auto take = [&](size_t bytes) -> char* {
    char* r = base + off;
    off += (bytes + 255) & ~(size_t)255;
    return r;
  };
  f16*   xf    = (f16*)  take((size_t)B_ * I_ * 2);
  f16*   gWf   = (f16*)  take((size_t)H_ * H_ * 2);
  f16*   cWf   = (f16*)  take((size_t)1024 * H_ * 2);
  float* cphi  = (float*)take((size_t)S_ * H_ * 4);
  float* sphi  = (float*)take((size_t)S_ * H_ * 4);
  f16*   act   = (f16*)  take((size_t)B_ * N1 * 2);
  float* mag0f = (float*)take((size_t)B_ * H_ * 4);
  f16*   mag0h = (f16*)  take((size_t)B_ * H_ * 2);
  float* mag1f = (float*)take((size_t)B_ * H_ * 4);
  f16*   mag1h = (f16*)  take((size_t)B_ * H_ * 2);
  float* msq   = (float*)take((size_t)B_ * H_ * 4);
  f16*   probs = (f16*)  take((size_t)B_ * H_ * 2);
  (void)ws_size; (void)in_sizes; (void)n_in; (void)out_size;

  // 0) converts (x, gW, cW) + phase tables (W stays f32)
  prep_kernel<<<(NTOT + 255) / 256, 256, 0, stream>>>(
      x, gW, cW, ph, xf, gWf, cWf, cphi, sphi);

  // 1) act = exp(-(x@W^T + b)^2): 256^2 ring, W staged in f32 via gload16
  gemm1_wf32<<<(B_ / 256) * (N1 / 256), 512, 0, stream>>>(xf, W, bb, act);

  // 2) normalize + supposition -> mag0 (LDS version)
  normsup_kernel<<<B_, 512, 0, stream>>>(act, cphi, sphi, mag0f, mag0h);

  // 3) gate step 1: mag1 = mag0 * sigmoid(mag0 @ gW^T + gb)  [128x64, 3 blk/CU]
  gemm_ring<128, 64, 2, 2, 256, 3, 1><<<(B_ / 128) * (H_ / 64), 256, 0, stream>>>(
      mag0h, gWf, H_, B_ / 128, H_, H_, gb,
      mag0f, mag1f, mag1h, nullptr, nullptr);

  // 4) gate step 2: msq = (mag1 * sigmoid(mag1 @ gW^T + gb))^2
  gemm_ring<128, 64, 2, 2, 256, 3, 1><<<(B_ / 128) * (H_ / 64), 256, 0, stream>>>(
      mag1h, gWf, H_, B_ / 128, H_, H_, gb,
      mag1f, nullptr, nullptr, msq, nullptr);

  // 5) top-256 + prob normalize
  topk_kernel<<<B_, 256, 0, stream>>>(msq, probs);

  // 6) logits = probs @ clf_W^T + clf_b  [128x64]
  gemm_ring<128, 64, 2, 2, 256, 3, 2><<<(B_ / 128) * (1024 / 64), 256, 0, stream>>>(
      probs, cWf, H_, B_ / 128, 0, C_, cb,
      nullptr, nullptr, nullptr, nullptr, out);
}

// Round 17
// 367.107 us; speedup vs baseline: 1.1030x; 1.1030x over previous
//
#include <hip/hip_runtime.h>

typedef _Float16 f16;
typedef _Float16 f16x8 __attribute__((ext_vector_type(8)));
typedef _Float16 f16x4 __attribute__((ext_vector_type(4)));
typedef float f32x4 __attribute__((ext_vector_type(4)));

#define B_    2048
#define I_    1024
#define H_    2048
#define C_    1000
#define S_    8
#define N1    32768   /* S * 2H */
#define TOPK_ 256

// ---------------- global -> LDS async stage (16B per lane) ----------------
__device__ __forceinline__ void gload16(const void* g, void* l) {
  __builtin_amdgcn_global_load_lds((const __attribute__((address_space(1))) void*)g,
                                   (__attribute__((address_space(3))) void*)l,
                                   16, 0, 0);
}

// ---------------- merged prep: all f32->f16 converts + phase tables ----------
#define NW8  (S_ * 2 * H_ * I_ / 8)
#define NX8  (B_ * I_ / 8)
#define NG8  (H_ * H_ / 8)
#define NC8  (1024 * H_ / 8)
#define NPH  (S_ * H_)
#define NTOT (NW8 + NX8 + NG8 + NC8 + NPH)

__global__ void prep_kernel(const float* __restrict__ W, const float* __restrict__ x,
                            const float* __restrict__ gW, const float* __restrict__ cW,
                            const float* __restrict__ ph,
                            f16* __restrict__ Wf, f16* __restrict__ xf,
                            f16* __restrict__ gWf, f16* __restrict__ cWf,
                            float* __restrict__ cphi, float* __restrict__ sphi)
{
  int i = blockIdx.x * blockDim.x + threadIdx.x;
  if (i >= NTOT) return;
  if (i < NW8 + NX8 + NG8 + NC8) {
    const float* src;
    f16* dst;
    int j = i;
    bool pad = false;
    if (j < NW8)                { src = W;  dst = Wf; }
    else if ((j -= NW8) < NX8)  { src = x;  dst = xf; }
    else if ((j -= NX8) < NG8)  { src = gW; dst = gWf; }
    else {
      j -= NG8; src = cW; dst = cWf;
      pad = (j >= C_ * H_ / 8);
    }
    f16x8 o;
    if (!pad) {
      const float4 a = reinterpret_cast<const float4*>(src)[2 * j];
      const float4 b = reinterpret_cast<const float4*>(src)[2 * j + 1];
      o = (f16x8){ (f16)a.x, (f16)a.y, (f16)a.z, (f16)a.w,
                   (f16)b.x, (f16)b.y, (f16)b.z, (f16)b.w };
    } else {
      o = (f16x8){ (f16)0.f, (f16)0.f, (f16)0.f, (f16)0.f,
                   (f16)0.f, (f16)0.f, (f16)0.f, (f16)0.f };
    }
    reinterpret_cast<f16x8*>(dst)[j] = o;
  } else {
    int j = i - (NW8 + NX8 + NG8 + NC8);
    float p = ph[j];
    cphi[j] = cosf(p);
    sphi[j] = sinf(p);
  }
}

// ================= GEMM1: 256x256, BK=32 ring-4, 8 waves (best-known) =========
__global__ __launch_bounds__(512, 1)
void gemm1_r4(const f16* __restrict__ A, const f16* __restrict__ Bm,
              const float* __restrict__ bias, f16* __restrict__ act)
{
  __shared__ char SL[131072];
  const int tid = threadIdx.x, lane = tid & 63, wid = tid >> 6;
  const int wr = wid >> 2, wc = wid & 3;       // 2M x 4N wave grid
  const int fr = lane & 15, fq = lane >> 4;
  const int bid = blockIdx.x;
  const int swz = (bid & 7) * 128 + (bid >> 3);   // XCD swizzle, 1024 blocks
  const int mt = swz & 7, nt = swz >> 3;
  const long brow = (long)mt * 256, bcol = (long)nt * 256;

  const int schunk = ((tid & 3) ^ ((tid >> 3) & 3)) * 8;
  const f16* srcP[4];
  srcP[0] = A  + (brow + (tid >> 2)) * (long)I_ + schunk;
  srcP[1] = A  + (brow + 128 + (tid >> 2)) * (long)I_ + schunk;
  srcP[2] = Bm + (bcol + (tid >> 2)) * (long)I_ + schunk;
  srcP[3] = Bm + (bcol + 128 + (tid >> 2)) * (long)I_ + schunk;

  const int co = (fq ^ ((fr >> 1) & 3)) * 16;
  const int rdA0 = (wr * 128 + fr) * 64 + co;
  const int rdB0 = 16384 + (wc * 64 + fr) * 64 + co;

  f32x4 acc[8][4] = {};

#define STG1(a, tt)                                                    \
  gload16(srcP[a] + (size_t)(tt) * 32,                                 \
          SL + ((tt) & 3) * 32768 + ((a) * 512 + tid) * 16)

  STG1(0,0); STG1(1,0); STG1(2,0); STG1(3,0);
  STG1(0,1); STG1(1,1); STG1(2,1); STG1(3,1);
  STG1(0,2); STG1(1,2); STG1(2,2); STG1(3,2);
  asm volatile("s_waitcnt vmcnt(8)" ::: "memory");
  __builtin_amdgcn_s_barrier();

#pragma unroll 1
  for (int t = 0; t < 32; ++t) {
    const char* rb = SL + (t & 3) * 32768;
    if (t < 29) { STG1(0, t + 3); STG1(1, t + 3); STG1(2, t + 3); STG1(3, t + 3); }

    f16x8 bf[4], af[8];
#pragma unroll
    for (int n = 0; n < 4; ++n) bf[n] = *(const f16x8*)(rb + rdB0 + n * 1024);
#pragma unroll
    for (int i = 0; i < 8; ++i) af[i] = *(const f16x8*)(rb + rdA0 + i * 1024);

    __builtin_amdgcn_s_setprio(1);
#pragma unroll
    for (int i = 0; i < 8; ++i)
#pragma unroll
      for (int n = 0; n < 4; ++n)
        acc[i][n] = __builtin_amdgcn_mfma_f32_16x16x32_f16(af[i], bf[n], acc[i][n], 0, 0, 0);
    __builtin_amdgcn_s_setprio(0);

    if (t < 29)       asm volatile("s_waitcnt vmcnt(8)" ::: "memory");
    else if (t == 29) asm volatile("s_waitcnt vmcnt(4)" ::: "memory");
    else              asm volatile("s_waitcnt vmcnt(0)" ::: "memory");
    __builtin_amdgcn_s_barrier();
  }
#undef STG1

  float bv[4];
#pragma unroll
  for (int n = 0; n < 4; ++n) bv[n] = bias[bcol + wc * 64 + n * 16 + fr];
#pragma unroll
  for (int m = 0; m < 8; ++m) {
    const long r0 = brow + wr * 128 + m * 16 + fq * 4;
#pragma unroll
    for (int n = 0; n < 4; ++n) {
      const long c = bcol + wc * 64 + n * 16 + fr;
#pragma unroll
      for (int j = 0; j < 4; ++j) {
        const float tt = acc[m][n][j] + bv[n];
        act[(r0 + j) * (long)N1 + c] = (f16)__expf(-tt * tt);
      }
    }
  }
}

// ================= generic ring-4 pipelined GEMM (gates / clf) =================
template<int BM, int BN, int WM, int WN, int THREADS, int MINW, int EPI>
__global__ __launch_bounds__(THREADS, MINW)
void gemm_ring(const f16* __restrict__ A, const f16* __restrict__ Bmat,
               const int K, const int MT, const int ldc, const int nreal,
               const float* __restrict__ bias,
               const float* __restrict__ magin,
               float* __restrict__ mago32, f16* __restrict__ mago16,
               float* __restrict__ msqout, float* __restrict__ logits)
{
  constexpr int MREP  = BM / (WM * 16);
  constexpr int NREP  = BN / (WN * 16);
  constexpr int CA    = (BM * 64) / (THREADS * 16);
  constexpr int CB    = (BN * 64) / (THREADS * 16);
  constexpr int CALLS = CA + CB;
  constexpr int SLOT  = (BM + BN) * 32;
  __shared__ f16 SL[4 * SLOT];

  const int tid  = threadIdx.x;
  const int lane = tid & 63, wid = tid >> 6;
  const int wr = wid / WN, wc = wid % WN;
  const int fr = lane & 15, fq = lane >> 4;

  const int nwg = gridDim.x;
  const int chunk = nwg >> 3;
  const int swz = (blockIdx.x & 7) * chunk + (blockIdx.x >> 3);
  const int mt = swz % MT, nt = swz / MT;
  const long brow = (long)mt * BM, bcol = (long)nt * BN;

  const f16* srcA[CA];
  const f16* srcB[CB];
#pragma unroll
  for (int a = 0; a < CA; ++a) {
    const int r = (a * THREADS + tid) >> 2;
    const int cs = (tid & 3) ^ ((r >> 1) & 3);
    srcA[a] = A + (size_t)(brow + r) * K + cs * 8;
  }
#pragma unroll
  for (int a = 0; a < CB; ++a) {
    const int r = (a * THREADS + tid) >> 2;
    const int cs = (tid & 3) ^ ((r >> 1) & 3);
    srcB[a] = Bmat + (size_t)(bcol + r) * K + cs * 8;
  }

  int ard[MREP], brd[NREP];
#pragma unroll
  for (int m = 0; m < MREP; ++m) {
    const int r = wr * MREP * 16 + m * 16 + fr;
    ard[m] = r * 32 + ((fq ^ ((r >> 1) & 3)) * 8);
  }
#pragma unroll
  for (int n = 0; n < NREP; ++n) {
    const int r = wc * NREP * 16 + n * 16 + fr;
    brd[n] = r * 32 + ((fq ^ ((r >> 1) & 3)) * 8);
  }

  f32x4 acc[MREP][NREP] = {};
  const int ntile = K >> 5;

#define STAGE_TILE(tt)                                                         \
  do {                                                                         \
    f16* D = &SL[((tt) & 3) * SLOT];                                           \
    const long kt = (long)(tt) * 32;                                           \
    _Pragma("unroll")                                                          \
    for (int a = 0; a < CA; ++a)                                               \
      gload16(srcA[a] + kt, D + a * THREADS * 8 + wid * 512);                  \
    _Pragma("unroll")                                                          \
    for (int a = 0; a < CB; ++a)                                               \
      gload16(srcB[a] + kt, D + BM * 32 + a * THREADS * 8 + wid * 512);        \
  } while (0)

  STAGE_TILE(0); STAGE_TILE(1); STAGE_TILE(2);

  for (int t = 0; t < ntile; ++t) {
    if (t + 3 < ntile) STAGE_TILE(t + 3);
    if (t < ntile - 3)       asm volatile("s_waitcnt vmcnt(%0)" :: "i"(3 * CALLS) : "memory");
    else if (t == ntile - 3) asm volatile("s_waitcnt vmcnt(%0)" :: "i"(2 * CALLS) : "memory");
    else if (t == ntile - 2) asm volatile("s_waitcnt vmcnt(%0)" :: "i"(1 * CALLS) : "memory");
    else                     asm volatile("s_waitcnt vmcnt(0)" ::: "memory");
    __builtin_amdgcn_s_barrier();
    asm volatile("" ::: "memory");

    const f16* SA = &SL[(t & 3) * SLOT];
    const f16* SB = SA + BM * 32;
    f16x8 af[MREP], bf[NREP];
#pragma unroll
    for (int m = 0; m < MREP; ++m) af[m] = *(const f16x8*)(SA + ard[m]);
#pragma unroll
    for (int n = 0; n < NREP; ++n) bf[n] = *(const f16x8*)(SB + brd[n]);

    __builtin_amdgcn_s_setprio(1);
#pragma unroll
    for (int m = 0; m < MREP; ++m)
#pragma unroll
      for (int n = 0; n < NREP; ++n)
        acc[m][n] = __builtin_amdgcn_mfma_f32_16x16x32_f16(af[m], bf[n], acc[m][n], 0, 0, 0);
    __builtin_amdgcn_s_setprio(0);
    asm volatile("" ::: "memory");
    __builtin_amdgcn_s_barrier();
  }
#undef STAGE_TILE

#pragma unroll
  for (int m = 0; m < MREP; ++m) {
    const long r0 = brow + wr * MREP * 16 + m * 16 + fq * 4;
#pragma unroll
    for (int n = 0; n < NREP; ++n) {
      const long c = bcol + wc * NREP * 16 + n * 16 + fr;
      float bv;
      if (EPI == 2) bv = (c < nreal) ? bias[c] : 0.f;
      else          bv = bias[c];
#pragma unroll
      for (int j = 0; j < 4; ++j) {
        const long r = r0 + j;
        const float t = acc[m][n][j] + bv;
        if (EPI == 1) {
          const float g = 1.f / (1.f + __expf(-t));
          const long idx = r * (long)ldc + c;
          const float v = magin[idx] * g;
          if (msqout) msqout[idx] = v * v;
          else { mago32[idx] = v; mago16[idx] = (f16)v; }
        } else {
          if (c < nreal) logits[r * (long)nreal + c] = t;
        }
      }
    }
  }
}

// ---------------- per-row norm + supposition -> mag0 (LDS version, proven) ----
__global__ __launch_bounds__(512)
void normsup_kernel(const f16* __restrict__ act,
                    const float* __restrict__ cphi, const float* __restrict__ sphi,
                    float* __restrict__ mag32, f16* __restrict__ mag16)
{
  __shared__ float buf[4096];
  __shared__ float red[8];
  const int b = blockIdx.x, tid = threadIdx.x;
  const int lane = tid & 63, wv = tid >> 6;
  float sr[4] = {0, 0, 0, 0}, si[4] = {0, 0, 0, 0};
  const f16* base = act + (size_t)b * N1;

  for (int s = 0; s < S_; ++s) {
    f16x8 v = *(const f16x8*)(base + s * 4096 + tid * 8);
    float ls = 0.f;
#pragma unroll
    for (int e = 0; e < 8; ++e) {
      float f = (float)v[e];
      buf[tid * 8 + e] = f;
      ls += f * f;
    }
#pragma unroll
    for (int o = 32; o > 0; o >>= 1) ls += __shfl_down(ls, o);
    if (lane == 0) red[wv] = ls;
    __syncthreads();
    const float tot = red[0] + red[1] + red[2] + red[3] + red[4] + red[5] + red[6] + red[7];
    const float factor = 1.f / sqrtf(tot + 1e-8f);

    const float4 c4 = *(const float4*)(cphi + s * H_ + tid * 4);
    const float4 s4 = *(const float4*)(sphi + s * H_ + tid * 4);
    const float4 a4 = *(const float4*)(&buf[tid * 4]);
    const float4 b4 = *(const float4*)(&buf[2048 + tid * 4]);
    sr[0] += factor * (a4.x * c4.x - b4.x * s4.x); si[0] += factor * (a4.x * s4.x + b4.x * c4.x);
    sr[1] += factor * (a4.y * c4.y - b4.y * s4.y); si[1] += factor * (a4.y * s4.y + b4.y * c4.y);
    sr[2] += factor * (a4.z * c4.z - b4.z * s4.z); si[2] += factor * (a4.z * s4.z + b4.z * c4.z);
    sr[3] += factor * (a4.w * c4.w - b4.w * s4.w); si[3] += factor * (a4.w * s4.w + b4.w * c4.w);
    __syncthreads();
  }

  const size_t o = (size_t)b * H_ + tid * 4;
  const float m0 = sqrtf(sr[0] * sr[0] + si[0] * si[0]);
  const float m1 = sqrtf(sr[1] * sr[1] + si[1] * si[1]);
  const float m2 = sqrtf(sr[2] * sr[2] + si[2] * si[2]);
  const float m3 = sqrtf(sr[3] * sr[3] + si[3] * si[3]);
  *(float4*)(mag32 + o) = make_float4(m0, m1, m2, m3);
  f16x4 mh = { (f16)m0, (f16)m1, (f16)m2, (f16)m3 };
  *(f16x4*)(mag16 + o) = mh;
}

// ---------------- top-k (256 of 2048) + prob normalize ----------------
__global__ __launch_bounds__(256)
void topk_kernel(const float* __restrict__ msq, f16* __restrict__ probs)
{
  __shared__ unsigned vals[2048];
  __shared__ int hist[256];
  __shared__ int scn[256];
  __shared__ int sdig, sknew;
  __shared__ float wsum[4];
  const int b = blockIdx.x, tid = threadIdx.x;
  const unsigned* row = (const unsigned*)(msq + (size_t)b * H_);

  uint4 v0 = *(const uint4*)(row + tid * 8);
  uint4 v1 = *(const uint4*)(row + tid * 8 + 4);
  vals[tid * 8 + 0] = v0.x; vals[tid * 8 + 1] = v0.y;
  vals[tid * 8 + 2] = v0.z; vals[tid * 8 + 3] = v0.w;
  vals[tid * 8 + 4] = v1.x; vals[tid * 8 + 5] = v1.y;
  vals[tid * 8 + 6] = v1.z; vals[tid * 8 + 7] = v1.w;
  __syncthreads();

  int k = TOPK_;
  unsigned prefix = 0, pmask = 0;
  for (int pass = 0; pass < 4; ++pass) {
    const int sh = 24 - pass * 8;
    hist[tid] = 0;
    __syncthreads();
#pragma unroll
    for (int e = 0; e < 8; ++e) {
      unsigned v = vals[tid * 8 + e];
      if ((v & pmask) == prefix) atomicAdd(&hist[(v >> sh) & 255u], 1);
    }
    __syncthreads();
    const int own = hist[tid];
    int sc = own;
    scn[tid] = sc;
    __syncthreads();
    for (int o2 = 1; o2 < 256; o2 <<= 1) {
      int add = (tid + o2 < 256) ? scn[tid + o2] : 0;
      __syncthreads();
      sc += add; scn[tid] = sc;
      __syncthreads();
    }
    if (sc >= k && (sc - own) < k) { sdig = tid; sknew = k - (sc - own); }
    __syncthreads();
    prefix |= ((unsigned)sdig) << sh;
    pmask  |= 0xFFu << sh;
    k = sknew;
    __syncthreads();
  }

  const unsigned T = prefix;
  const int krem = k;
  unsigned vl[8];
  int eqc = 0;
#pragma unroll
  for (int e = 0; e < 8; ++e) { vl[e] = vals[tid * 8 + e]; if (vl[e] == T) eqc++; }
  int sc2 = eqc;
  scn[tid] = sc2;
  __syncthreads();
  for (int o2 = 1; o2 < 256; o2 <<= 1) {
    int add = (tid >= o2) ? scn[tid - o2] : 0;
    __syncthreads();
    sc2 += add; scn[tid] = sc2;
    __syncthreads();
  }
  int rank = sc2 - eqc;
  float ls = 0.f;
  bool sel[8];
#pragma unroll
  for (int e = 0; e < 8; ++e) {
    const unsigned v = vl[e];
    bool s_ = false;
    if (v > T) s_ = true;
    else if (v == T) { s_ = (rank < krem); ++rank; }
    sel[e] = s_;
    if (s_) ls += __uint_as_float(v);
  }
#pragma unroll
  for (int o2 = 32; o2 > 0; o2 >>= 1) ls += __shfl_down(ls, o2);
  if ((tid & 63) == 0) wsum[tid >> 6] = ls;
  __syncthreads();
  const float tot = wsum[0] + wsum[1] + wsum[2] + wsum[3];
  const float inv = 1.f / (tot + 1e-8f);
  f16x8 ov;
#pragma unroll
  for (int e = 0; e < 8; ++e)
    ov[e] = sel[e] ? (f16)(__uint_as_float(vl[e]) * inv) : (f16)0.f;
  *(f16x8*)(probs + (size_t)b * H_ + tid * 8) = ov;
}

// ---------------- launch ----------------
extern "C" void kernel_launch(void* const* d_in, const int* in_sizes, int n_in,
                              void* d_out, int out_size, void* d_ws, size_t ws_size,
                              hipStream_t stream)
{
  const float* x  = (const float*)d_in[0];
  const float* W  = (const float*)d_in[1];
  const float* bb = (const float*)d_in[2];
  const float* ph = (const float*)d_in[3];
  const float* gW = (const float*)d_in[4];
  const float* gb = (const float*)d_in[5];
  const float* cW = (const float*)d_in[6];
  const float* cb = (const float*)d_in[7];
  float* out = (float*)d_out;

  char* base = (char*)d_ws;
  size_t off = 0;
  auto take = [&](size_t bytes) -> char* {
    char* r = base + off;
    off += (bytes + 255) & ~(size_t)255;
    return r;
  };
  f16*   Wf    = (f16*)  take((size_t)S_ * 2 * H_ * I_ * 2);
  f16*   xf    = (f16*)  take((size_t)B_ * I_ * 2);
  f16*   gWf   = (f16*)  take((size_t)H_ * H_ * 2);
  f16*   cWf   = (f16*)  take((size_t)1024 * H_ * 2);
  float* cphi  = (float*)take((size_t)S_ * H_ * 4);
  float* sphi  = (float*)take((size_t)S_ * H_ * 4);
  f16*   act   = (f16*)  take((size_t)B_ * N1 * 2);
  float* mag0f = (float*)take((size_t)B_ * H_ * 4);
  f16*   mag0h = (f16*)  take((size_t)B_ * H_ * 2);
  float* mag1f = (float*)take((size_t)B_ * H_ * 4);
  f16*   mag1h = (f16*)  take((size_t)B_ * H_ * 2);
  float* msq   = (float*)take((size_t)B_ * H_ * 4);
  f16*   probs = (f16*)  take((size_t)B_ * H_ * 2);
  (void)ws_size; (void)in_sizes; (void)n_in; (void)out_size;

  // 0) all converts + phase tables in one launch
  prep_kernel<<<(NTOT + 255) / 256, 256, 0, stream>>>(
      W, x, gW, cW, ph, Wf, xf, gWf, cWf, cphi, sphi);

  // 1) act = exp(-(x@W^T + b)^2): 256^2 BK=32 ring-4 pipelined GEMM
  gemm1_r4<<<(B_ / 256) * (N1 / 256), 512, 0, stream>>>(xf, Wf, bb, act);

  // 2) normalize + supposition -> mag0 (LDS version)
  normsup_kernel<<<B_, 512, 0, stream>>>(act, cphi, sphi, mag0f, mag0h);

  // 3) gate step 1: mag1 = mag0 * sigmoid(mag0 @ gW^T + gb)  [128x64, 3 blk/CU]
  gemm_ring<128, 64, 2, 2, 256, 3, 1><<<(B_ / 128) * (H_ / 64), 256, 0, stream>>>(
      mag0h, gWf, H_, B_ / 128, H_, H_, gb,
      mag0f, mag1f, mag1h, nullptr, nullptr);

  // 4) gate step 2: msq = (mag1 * sigmoid(mag1 @ gW^T + gb))^2
  gemm_ring<128, 64, 2, 2, 256, 3, 1><<<(B_ / 128) * (H_ / 64), 256, 0, stream>>>(
      mag1h, gWf, H_, B_ / 128, H_, H_, gb,
      mag1f, nullptr, nullptr, msq, nullptr);

  // 5) top-256 + prob normalize
  topk_kernel<<<B_, 256, 0, stream>>>(msq, probs);

  // 6) logits = probs @ clf_W^T + clf_b  [128x64]
  gemm_ring<128, 64, 2, 2, 256, 3, 2><<<(B_ / 128) * (1024 / 64), 256, 0, stream>>>(
      probs, cWf, H_, B_ / 128, 0, C_, cb,
      nullptr, nullptr, nullptr, nullptr, out);
}